// Round 1
// 765.189 us; speedup vs baseline: 1.0019x; 1.0019x over previous
//
#include <hip/hip_runtime.h>
#include <math.h>

// N=8192, D=256, F=64
#define NN 8192
#define DD 256
#define FF 64

// q is pre-scaled by softmax scale * log2(e) so attention works in exp2 domain
#define QSC (0.125f * 1.4426950408889634f)

typedef __attribute__((ext_vector_type(8))) __bf16 bf16x8;
typedef __attribute__((ext_vector_type(4))) __bf16 bf16x4;
typedef __attribute__((ext_vector_type(4))) float f32x4;

static __device__ __forceinline__ f32x4 mfma16(bf16x8 a, bf16x8 b, f32x4 c) {
    return __builtin_amdgcn_mfma_f32_16x16x32_bf16(a, b, c, 0, 0, 0);
}

// ---------------------------------------------------------------------------
// Kernel 1a: per-node Q projection (streams the 512 MB Wq — the HBM term).
// One block per node i; wave w covers f = w*16..w*16+15.
// Phase 1: lane l keeps 16 register partials pf[ff] = Wq[i,f,4l..4l+3]·x[i,4l..4l+3]
// Phase 2: wave-private LDS transpose (padded stride 17 -> <=2-way banks),
//          4 lanes/f sum 16 partials each, 2 shfl_xor finish.
// (unchanged this round — modeled at the 512 MiB HBM floor)
// ---------------------------------------------------------------------------
__global__ __launch_bounds__(256) void proj_q_kernel(
    const float* __restrict__ x, const float* __restrict__ Wq,
    const float* __restrict__ bq, __bf16* __restrict__ q_bf)
{
    __shared__ float T[4][64 * 17];

    const int i = blockIdx.x;
    const int l = threadIdx.x & 63;
    const int w = threadIdx.x >> 6;

    const float4 xf = reinterpret_cast<const float4*>(x)[(size_t)i * 64 + l];
    const float4* wq4 = reinterpret_cast<const float4*>(Wq) + (size_t)i * 4096;

    float pf[16];
#pragma unroll
    for (int ff = 0; ff < 16; ++ff) {
        const int f = w * 16 + ff;
        float4 a = wq4[f * 64 + l];
        pf[ff] = a.x * xf.x + a.y * xf.y + a.z * xf.z + a.w * xf.w;
    }
#pragma unroll
    for (int ff = 0; ff < 16; ++ff) T[w][l * 17 + ff] = pf[ff];
    // wave-private tile: no barrier needed
    const int f = l & 15;
    const int c = l >> 4;
    float s = 0.f;
#pragma unroll
    for (int j = 0; j < 16; ++j) s += T[w][(c * 16 + j) * 17 + f];
    s += __shfl_xor(s, 16, 64);
    s += __shfl_xor(s, 32, 64);
    if (l < 16)
        q_bf[(size_t)i * FF + w * 16 + l] =
            (__bf16)((s + bq[(size_t)i * FF + w * 16 + l]) * QSC);
}

// ---------------------------------------------------------------------------
// Kernel 1b: shared K/V projections as a small MFMA GEMM. (unchanged)
// ---------------------------------------------------------------------------
__global__ __launch_bounds__(256) void proj_kv_kernel(
    const float* __restrict__ x, const float* __restrict__ Wk,
    const float* __restrict__ bk, const float* __restrict__ Wv,
    const float* __restrict__ bv,
    __bf16* __restrict__ k_bf, __bf16* __restrict__ vT)
{
    const int lane = threadIdx.x & 63;
    const int wave = threadIdx.x >> 6;
    const int g = lane >> 4;
    const int qc = lane & 15;
    const int i0 = blockIdx.x * 64 + wave * 16;  // wave's 16-row i-tile

    f32x4 ack[4], acv[4];
#pragma unroll
    for (int nt = 0; nt < 4; ++nt) {
        ack[nt] = (f32x4){0.f, 0.f, 0.f, 0.f};
        acv[nt] = (f32x4){0.f, 0.f, 0.f, 0.f};
    }

    const float4* x4 = reinterpret_cast<const float4*>(x);
#pragma unroll
    for (int ks = 0; ks < 8; ++ks) {
        float4 xa = x4[(size_t)(i0 + qc) * 64 + ks * 8 + g * 2];
        float4 xb = x4[(size_t)(i0 + qc) * 64 + ks * 8 + g * 2 + 1];
        bf16x8 af;
        af[0] = (__bf16)xa.x; af[1] = (__bf16)xa.y; af[2] = (__bf16)xa.z; af[3] = (__bf16)xa.w;
        af[4] = (__bf16)xb.x; af[5] = (__bf16)xb.y; af[6] = (__bf16)xb.z; af[7] = (__bf16)xb.w;
#pragma unroll
        for (int nt = 0; nt < 4; ++nt) {
            const float* wkp = Wk + (size_t)(nt * 16 + qc) * DD + ks * 32 + g * 8;
            const float* wvp = Wv + (size_t)(nt * 16 + qc) * DD + ks * 32 + g * 8;
            float4 wa = reinterpret_cast<const float4*>(wkp)[0];
            float4 wb = reinterpret_cast<const float4*>(wkp)[1];
            bf16x8 bk8;
            bk8[0] = (__bf16)wa.x; bk8[1] = (__bf16)wa.y; bk8[2] = (__bf16)wa.z; bk8[3] = (__bf16)wa.w;
            bk8[4] = (__bf16)wb.x; bk8[5] = (__bf16)wb.y; bk8[6] = (__bf16)wb.z; bk8[7] = (__bf16)wb.w;
            ack[nt] = mfma16(af, bk8, ack[nt]);
            float4 va = reinterpret_cast<const float4*>(wvp)[0];
            float4 vb = reinterpret_cast<const float4*>(wvp)[1];
            bf16x8 bv8;
            bv8[0] = (__bf16)va.x; bv8[1] = (__bf16)va.y; bv8[2] = (__bf16)va.z; bv8[3] = (__bf16)va.w;
            bv8[4] = (__bf16)vb.x; bv8[5] = (__bf16)vb.y; bv8[6] = (__bf16)vb.z; bv8[7] = (__bf16)vb.w;
            acv[nt] = mfma16(af, bv8, acv[nt]);
        }
    }

#pragma unroll
    for (int nt = 0; nt < 4; ++nt) {
        const int f = nt * 16 + qc;
        const float bkf = bk[f];
        const float bvf = bv[f];
#pragma unroll
        for (int r = 0; r < 4; ++r) {
            const int i = i0 + g * 4 + r;
            k_bf[(size_t)i * FF + f] = (__bf16)(ack[nt][r] + bkf);
            vT[(size_t)f * NN + i]   = (__bf16)(acv[nt][r] + bvf);
        }
    }
}

// ---------------------------------------------------------------------------
// Kernel 2 (v2): flash attention, transposed-score formulation.
// Changes this round:
//  * Double-buffered K/V LDS tiles with async-stage split (T14): next tile's
//    global loads are issued at the TOP of the iteration (latency hides under
//    S/softmax/PV compute); ds_write to the alternate buffer happens after
//    compute. vmcnt wait lands after ~600 cycles of compute -> no stall.
//  * ONE __syncthreads per iteration (was 2): with 2 buffers, the write to
//    buf 1-c only conflicts with reads that completed before the previous
//    iteration's barrier.
//  * s_setprio(1) around both MFMA clusters (T5).
//  * defer-max (T13): skip O/l rescale when __all(mt - mrun <= 10) (log2
//    domain; P bounded by 2^10, safe in bf16 with fp32 accum; math exact
//    since m/l/Om partials stay mutually consistent).
// ---------------------------------------------------------------------------
__global__ __launch_bounds__(256) void attn_kernel(
    const __bf16* __restrict__ q_bf, const __bf16* __restrict__ k_bf,
    const __bf16* __restrict__ vT,
    float* __restrict__ Om, float* __restrict__ m_arr, float* __restrict__ l_arr,
    int kv_per_split)
{
    __shared__ __align__(16) __bf16 Klds[2][64 * 64];   // [buf][key-row][f], blk^=(row&7)
    __shared__ __align__(16) __bf16 Vlds[2][64 * 64];   // [buf][f-row][key], blk^=(row&7)
    __shared__ __align__(16) __bf16 pT[4][16 * 64];     // per-wave P^T, blk^=(qc&7)

    const int t = threadIdx.x;
    const int lane = t & 63;
    const int wave = t >> 6;
    const int g = lane >> 4;
    const int qc = lane & 15;
    const int q0 = blockIdx.x * 64 + wave * 16;
    const int s  = blockIdx.y;
    const int qrow = q0 + qc;
    const int sw = qc & 7;

    // staging map: thread t -> row = t>>2, 16B-unit pair bp = (t&3)*2
    const int srow = t >> 2;
    const int sbp  = (t & 3) * 2;
    const int so0 = srow * 64 + ((sbp ^ (srow & 7)) * 8);
    const int so1 = srow * 64 + (((sbp + 1) ^ (srow & 7)) * 8);

    const bf16x8 qf0 = *reinterpret_cast<const bf16x8*>(q_bf + (size_t)qrow * FF + g * 8);
    const bf16x8 qf1 = *reinterpret_cast<const bf16x8*>(q_bf + (size_t)qrow * FF + 32 + g * 8);

    f32x4 o[4];
#pragma unroll
    for (int m = 0; m < 4; ++m) o[m] = (f32x4){0.f, 0.f, 0.f, 0.f};
    float mrun = -INFINITY;
    float lrun = 0.f;

    const int kv0 = s * kv_per_split;
    const int niter = kv_per_split >> 6;

    const __bf16* ksrc = k_bf + (size_t)srow * FF + sbp * 8;  // + kb*FF
    const __bf16* vsrc = vT  + (size_t)srow * NN + sbp * 8;   // + kb

    // prologue: stage tile 0 into buf 0
    bf16x8 u0 = *reinterpret_cast<const bf16x8*>(ksrc + (size_t)kv0 * FF);
    bf16x8 u1 = *reinterpret_cast<const bf16x8*>(ksrc + (size_t)kv0 * FF + 8);
    bf16x8 w0 = *reinterpret_cast<const bf16x8*>(vsrc + kv0);
    bf16x8 w1 = *reinterpret_cast<const bf16x8*>(vsrc + kv0 + 8);
    *reinterpret_cast<bf16x8*>(&Klds[0][so0]) = u0;
    *reinterpret_cast<bf16x8*>(&Klds[0][so1]) = u1;
    *reinterpret_cast<bf16x8*>(&Vlds[0][so0]) = w0;
    *reinterpret_cast<bf16x8*>(&Vlds[0][so1]) = w1;
    __syncthreads();

    for (int it = 0; it < niter; ++it) {
        const int cur = it & 1;
        // ---- issue next tile's global loads (clamped reload on last iter) ----
        const int itn = (it + 1 < niter) ? (it + 1) : it;
        const int kbn = kv0 + itn * 64;
        u0 = *reinterpret_cast<const bf16x8*>(ksrc + (size_t)kbn * FF);
        u1 = *reinterpret_cast<const bf16x8*>(ksrc + (size_t)kbn * FF + 8);
        w0 = *reinterpret_cast<const bf16x8*>(vsrc + kbn);
        w1 = *reinterpret_cast<const bf16x8*>(vsrc + kbn + 8);

        const __bf16* Kb = &Klds[cur][0];
        const __bf16* Vb = &Vlds[cur][0];

        // ---- S^T = K · Q^T (scores pre-scaled, log2 domain) ----
        f32x4 sc[4];
        __builtin_amdgcn_s_setprio(1);
#pragma unroll
        for (int kt = 0; kt < 4; ++kt) {
            const int row = kt * 16 + qc;
            bf16x8 a0 = *reinterpret_cast<const bf16x8*>(&Kb[row * 64 + ((g ^ sw) * 8)]);
            bf16x8 a1 = *reinterpret_cast<const bf16x8*>(&Kb[row * 64 + (((4 + g) ^ sw) * 8)]);
            f32x4 acc = (f32x4){0.f, 0.f, 0.f, 0.f};
            acc = mfma16(a0, qf0, acc);
            acc = mfma16(a1, qf1, acc);
            sc[kt] = acc;
        }
        __builtin_amdgcn_s_setprio(0);

        // ---- online softmax (per-lane stats, defer-max) ----
        float mt = fmaxf(fmaxf(sc[0].x, sc[0].y), fmaxf(sc[0].z, sc[0].w));
#pragma unroll
        for (int kt = 1; kt < 4; ++kt)
            mt = fmaxf(mt, fmaxf(fmaxf(sc[kt].x, sc[kt].y), fmaxf(sc[kt].z, sc[kt].w)));
        mt = fmaxf(mt, __shfl_xor(mt, 16, 64));
        mt = fmaxf(mt, __shfl_xor(mt, 32, 64));

        if (!__all(mt - mrun <= 10.0f)) {
            const float mnew = fmaxf(mrun, mt);
            const float alpha = __builtin_amdgcn_exp2f(mrun - mnew);
            lrun *= alpha;
#pragma unroll
            for (int m = 0; m < 4; ++m) o[m] *= alpha;
            mrun = mnew;
        }

        float psum = 0.f;
#pragma unroll
        for (int kt = 0; kt < 4; ++kt) {
            float p0 = __builtin_amdgcn_exp2f(sc[kt].x - mrun);
            float p1 = __builtin_amdgcn_exp2f(sc[kt].y - mrun);
            float p2 = __builtin_amdgcn_exp2f(sc[kt].z - mrun);
            float p3 = __builtin_amdgcn_exp2f(sc[kt].w - mrun);
            psum += (p0 + p1) + (p2 + p3);
            bf16x4 pv;
            pv[0] = (__bf16)p0; pv[1] = (__bf16)p1;
            pv[2] = (__bf16)p2; pv[3] = (__bf16)p3;
            const int b = kt * 2 + (g >> 1);
            *reinterpret_cast<bf16x4*>(&pT[wave][qc * 64 + ((b ^ sw) << 3) + (g & 1) * 4]) = pv;
        }
        psum += __shfl_xor(psum, 16, 64);
        psum += __shfl_xor(psum, 32, 64);
        lrun += psum;

        // ---- O^T += V^T · P^T ----
        __builtin_amdgcn_s_setprio(1);
#pragma unroll
        for (int kk = 0; kk < 2; ++kk) {
            const int br = kk * 4 + g;
            bf16x8 pb = *reinterpret_cast<const bf16x8*>(&pT[wave][qc * 64 + ((br ^ sw) << 3)]);
#pragma unroll
            for (int m = 0; m < 4; ++m) {
                const int row = m * 16 + qc;
                bf16x8 a = *reinterpret_cast<const bf16x8*>(
                    &Vb[row * 64 + ((br ^ sw) * 8)]);
                o[m] = mfma16(a, pb, o[m]);
            }
        }
        __builtin_amdgcn_s_setprio(0);

        // ---- write next tile into alternate buffer; single barrier ----
        *reinterpret_cast<bf16x8*>(&Klds[cur ^ 1][so0]) = u0;
        *reinterpret_cast<bf16x8*>(&Klds[cur ^ 1][so1]) = u1;
        *reinterpret_cast<bf16x8*>(&Vlds[cur ^ 1][so0]) = w0;
        *reinterpret_cast<bf16x8*>(&Vlds[cur ^ 1][so1]) = w1;
        __syncthreads();
    }

    // ---- store partials: Om[s][f][i], f = m*16 + g*4 + r ----
    float* op = Om + (size_t)s * FF * NN;
#pragma unroll
    for (int m = 0; m < 4; ++m) {
        op[(size_t)(m * 16 + g * 4 + 0) * NN + q0 + qc] = o[m].x;
        op[(size_t)(m * 16 + g * 4 + 1) * NN + q0 + qc] = o[m].y;
        op[(size_t)(m * 16 + g * 4 + 2) * NN + q0 + qc] = o[m].z;
        op[(size_t)(m * 16 + g * 4 + 3) * NN + q0 + qc] = o[m].w;
    }
    if (g == 0) {
        m_arr[s * NN + qrow] = mrun;   // log2 domain
        l_arr[s * NN + qrow] = lrun;
    }
}

// ---------------------------------------------------------------------------
// Kernel 3: merge nsplit partials (log2-domain LSE) -> fp32 out[i][f].
// ---------------------------------------------------------------------------
__global__ __launch_bounds__(256) void combine_kernel(
    const float* __restrict__ Om, const float* __restrict__ m_arr,
    const float* __restrict__ l_arr, float* __restrict__ out, int nsplit)
{
    const int idx = blockIdx.x * 256 + threadIdx.x;  // < FF*NN
    const int f = idx >> 13;
    const int i = idx & (NN - 1);

    float M = -INFINITY;
    for (int s = 0; s < nsplit; ++s) M = fmaxf(M, m_arr[s * NN + i]);
    float L = 0.f, acc = 0.f;
    for (int s = 0; s < nsplit; ++s) {
        float wgt = __builtin_amdgcn_exp2f(m_arr[s * NN + i] - M);
        L   += wgt * l_arr[s * NN + i];
        acc += wgt * Om[((size_t)s * FF + f) * NN + i];
    }
    out[(size_t)i * FF + f] = acc / L;
}

// ---------------------------------------------------------------------------
// ws layout: q_bf 1 MiB | k_bf 1 MiB | vT 1 MiB | Om nsplit*2 MiB | m | l
// ---------------------------------------------------------------------------
extern "C" void kernel_launch(void* const* d_in, const int* in_sizes, int n_in,
                              void* d_out, int out_size, void* d_ws, size_t ws_size,
                              hipStream_t stream) {
    const float* x  = (const float*)d_in[0];
    const float* Wk = (const float*)d_in[1];
    const float* bk = (const float*)d_in[2];
    const float* Wv = (const float*)d_in[3];
    const float* bv = (const float*)d_in[4];
    const float* Wq = (const float*)d_in[5];
    const float* bq = (const float*)d_in[6];
    float* out = (float*)d_out;

    const int nsplit = (ws_size >= (size_t)20971520) ? 8 : 4;
    const int kv_per_split = NN / nsplit;

    char* ws = (char*)d_ws;
    __bf16* q_bf = (__bf16*)(ws);
    __bf16* k_bf = (__bf16*)(ws + ((size_t)1 << 20));
    __bf16* vT   = (__bf16*)(ws + ((size_t)2 << 20));
    float*  Om   = (float*)(ws + ((size_t)3 << 20));
    float*  m_a  = (float*)(ws + ((size_t)3 << 20) + (size_t)nsplit * FF * NN * 4);
    float*  l_a  = (float*)((char*)m_a + (size_t)nsplit * NN * 4);

    hipLaunchKernelGGL(proj_q_kernel, dim3(NN), dim3(256), 0, stream,
                       x, Wq, bq, q_bf);
    hipLaunchKernelGGL(proj_kv_kernel, dim3(NN / 64), dim3(256), 0, stream,
                       x, Wk, bk, Wv, bv, k_bf, vT);
    hipLaunchKernelGGL(attn_kernel, dim3(NN / 64, nsplit), dim3(256), 0, stream,
                       q_bf, k_bf, vT, Om, m_a, l_a, kv_per_split);
    hipLaunchKernelGGL(combine_kernel, dim3(NN * FF / 256), dim3(256), 0, stream,
                       Om, m_a, l_a, out, nsplit);
}